// Round 19
// baseline (84.668 us; speedup 1.0000x reference)
//
#include <hip/hip_runtime.h>
#include <hip/hip_bf16.h>

// MultiLinear: y[b,g,o] = sum_i x[b,g,i] * W[g,o,i] + bias[g,o]
// B=4096, G=16, DIN=512, DOUT=512, fp32 in/out.
// R19: BK=128 / NT=4 (2x bigger K-phases, half the barrier events).
// Enabler: B is PER-WAVE PRIVATE (each wave DMAs + reads only its own 64
// rows) -> B needs no barrier, can be SINGLE-buffered (128 KB), refilled
// right after the wave's own reads, synced by counted vmcnt alone.
// A (block-shared) single-buffered 32 KB with the unavoidable per-tile
// RAW barrier pair. LDS = 160 KB exact. Keeps R15's verified traffic
// profile: X read once (BN=512), W bf16-prepass L2-resident, XCD swizzle,
// chunk-XOR bank-floor swizzles (re-derived for 256-B rows), counted vmcnt
// that never drains the A-prefetch.

#define BATCH 4096
#define NGRP  16
#define DIN   512
#define DOUT  512

#define BM 128
#define BN 512
#define BK 128
#define NT (DIN / BK)   // 4 K-tiles

typedef __bf16 bf16x8 __attribute__((ext_vector_type(8)));
typedef __bf16 bf16x4 __attribute__((ext_vector_type(4)));
typedef float  f32x4  __attribute__((ext_vector_type(4)));
typedef const __attribute__((address_space(1))) void gas_void;
typedef __attribute__((address_space(3))) void las_void;

// ---------- prepass: W fp32 -> bf16 into d_ws ----------
__global__ __launch_bounds__(256)
void wcvt_kernel(const float* __restrict__ W, __bf16* __restrict__ Wb) {
    const int i = (blockIdx.x * 256 + threadIdx.x) * 8;
    f32x4 a = *(const f32x4*)(W + i);
    f32x4 b = *(const f32x4*)(W + i + 4);
    bf16x8 v;
#pragma unroll
    for (int j = 0; j < 4; ++j) { v[j] = (__bf16)a[j]; v[j + 4] = (__bf16)b[j]; }
    *(bf16x8*)(Wb + i) = v;
}

// ---------- main GEMM ----------
__global__ __launch_bounds__(512, 2)
void MultiLinear_48498770706571_kernel(const float* __restrict__ X,
                                       const __bf16* __restrict__ Wb,
                                       const float* __restrict__ Bias,
                                       float* __restrict__ Y) {
    // 512 blocks / 8 XCDs = 64 consecutive tiles (2 full groups) per XCD.
    const int bid = (blockIdx.x & 7) * 64 + (blockIdx.x >> 3);
    const int g   = bid >> 5;          // 32 m-tiles per group, 1 n-tile
    const int mt  = bid & 31;
    const int bm0 = mt * BM;

    __shared__ __bf16 As[BM * BK];     // 32 KB single-buffer, 256B rows
    __shared__ __bf16 BsF[BN * BK];    // 128 KB single-buffer, per-wave rows

    const int tid  = threadIdx.x;
    const int lane = tid & 63;
    const int w    = tid >> 6;        // 0..7
    const int wn   = w * 64;          // wave n-offset (wm = 0 for all)
    const int l15  = lane & 15;
    const int q    = lane >> 4;       // 0..3

    // A staging: 4 thr/row, 32 floats each in 8 x 16B pieces at stride 64B
    // (64B-coalesced: threads 0-3 cover 64B contiguous per piece-index j).
    const int srow = tid >> 2;        // 0..127
    const int tq   = tid & 3;
    const float* pA = X + (size_t)(bm0 + srow) * (NGRP * DIN) + g * DIN + tq * 4;

    // B DMA: per wave 64 rows x 256 B = 16 instrs of 1 KB (4 rows x 16 chunks)
    const int drow_l = lane >> 4;     // 0..3 row within instr
    const int dc     = lane & 15;     // 16B chunk within row
    const __bf16* wbase = Wb + (size_t)g * (DOUT * DIN);

    f32x4 ra[8];   // 32 VGPRs in flight (A only; B is DMA)

#define ISSUE_A(k0)                                                        \
    do {                                                                   \
        _Pragma("unroll")                                                  \
        for (int j = 0; j < 8; ++j)                                        \
            ra[j] = *(const f32x4*)(pA + (k0) + j * 16);                   \
    } while (0)

    // A write: piece j = logical elems tq*4 + j*16 -> chunk lc=j*2+(tq>>1),
    // half tq&1; phys chunk = (lc&8) | ((lc&7) ^ (srow&7)); b64 writes.
#define CVT_WRITE_A()                                                      \
    do {                                                                   \
        const int s = srow & 7;                                            \
        const int hb = (tq & 1) * 4;                                       \
        _Pragma("unroll")                                                  \
        for (int j = 0; j < 8; ++j) {                                      \
            bf16x4 v;                                                      \
            _Pragma("unroll")                                              \
            for (int e = 0; e < 4; ++e) v[e] = (__bf16)ra[j][e];           \
            const int lc   = j * 2 + (tq >> 1);                            \
            const int phys = (lc & 8) | ((lc & 7) ^ s);                    \
            *(bf16x4*)&As[srow * BK + phys * 8 + hb] = v;                  \
        }                                                                  \
    } while (0)

    // B: LDS linear dest (own 64 rows); global source pre-swizzled.
#define DMA_B(kt)                                                          \
    do {                                                                   \
        const size_t k0 = (size_t)(kt) * BK;                               \
        _Pragma("unroll")                                                  \
        for (int qq = 0; qq < 16; ++qq) {                                  \
            const int row  = (w << 6) + (qq << 2) + drow_l;                \
            const int csrc = (dc & 8) | ((dc & 7) ^ (row & 7));            \
            const __bf16* gp = wbase + (size_t)row * DIN + k0              \
                               + (csrc << 3);                              \
            __builtin_amdgcn_global_load_lds(                              \
                (gas_void*)gp,                                             \
                (las_void*)&BsF[((w << 6) + (qq << 2)) * BK], 16, 0, 0);   \
        }                                                                  \
    } while (0)

#define COMPUTE()                                                          \
    do {                                                                   \
        _Pragma("unroll")                                                  \
        for (int kk = 0; kk < 4; ++kk) {                                   \
            bf16x8 af[8], bfr[4];                                          \
            const int chl = (kk << 2) + q;                                 \
            _Pragma("unroll")                                              \
            for (int mi = 0; mi < 8; ++mi) {                               \
                const int row  = mi * 16 + l15;                            \
                const int phys = (chl & 8) | ((chl & 7) ^ (row & 7));      \
                af[mi] = *(const bf16x8*)&As[row * BK + (phys << 3)];      \
            }                                                              \
            _Pragma("unroll")                                              \
            for (int ni = 0; ni < 4; ++ni) {                               \
                const int brow = wn + ni * 16 + l15;                       \
                const int phys = (chl & 8) | ((chl & 7) ^ (brow & 7));     \
                bfr[ni] = *(const bf16x8*)&BsF[brow * BK + (phys << 3)];   \
            }                                                              \
            _Pragma("unroll")                                              \
            for (int mi = 0; mi < 8; ++mi)                                 \
                _Pragma("unroll")                                          \
                for (int ni = 0; ni < 4; ++ni)                             \
                    acc[mi][ni] = __builtin_amdgcn_mfma_f32_16x16x32_bf16( \
                        af[mi], bfr[ni], acc[mi][ni], 0, 0, 0);            \
        }                                                                  \
    } while (0)

    f32x4 acc[8][4];
#pragma unroll
    for (int mi = 0; mi < 8; ++mi)
#pragma unroll
        for (int ni = 0; ni < 4; ++ni) acc[mi][ni] = f32x4{0.f, 0.f, 0.f, 0.f};

    // prologue: tile 0. Order: ra(0) first, DMA(0) second -> CVT's implicit
    // wait (vmcnt(16)) drains ra(0) only, DMA(0) stays in flight.
    ISSUE_A(0);
    DMA_B(0);
    CVT_WRITE_A();
    ISSUE_A(BK);          // ra(1); outstanding: DMA(0)[16] + ra(1)[8]
    asm volatile("s_waitcnt lgkmcnt(0)" ::: "memory");
    __builtin_amdgcn_s_barrier();     // A(0) visible to all waves

    for (int kt = 0; kt < NT; ++kt) {
        // Drain own DMA(kt) (16 oldest); keep ra(kt+1) (8 newer) in flight.
        if (kt + 1 < NT)
            asm volatile("s_waitcnt vmcnt(8)" ::: "memory");
        else
            asm volatile("s_waitcnt vmcnt(0)" ::: "memory");  // last: DMA only

        COMPUTE();   // reads A(kt) [shared, barrier-published] + B(kt) [own]

        if (kt + 1 < NT) {
            asm volatile("s_waitcnt lgkmcnt(0)" ::: "memory");
            __builtin_amdgcn_s_barrier();   // BAR1: all A(kt) reads done (WAR)
            DMA_B(kt + 1);                  // own B refill (reads done above)
            CVT_WRITE_A();                  // implicit vmcnt(16): waits ra only
            if (kt + 2 < NT) ISSUE_A((kt + 2) * BK);
            asm volatile("s_waitcnt lgkmcnt(0)" ::: "memory");
            __builtin_amdgcn_s_barrier();   // BAR2: A(kt+1) visible (RAW)
        }
    }

    // epilogue: C/D layout col = lane&15, row = (lane>>4)*4 + j (verified R1)
    const int r0 = (lane >> 4) * 4;
    const int c  = lane & 15;
    float bias_n[4];
#pragma unroll
    for (int ni = 0; ni < 4; ++ni)
        bias_n[ni] = Bias[g * DOUT + wn + ni * 16 + c];
#pragma unroll
    for (int mi = 0; mi < 8; ++mi) {
#pragma unroll
        for (int j = 0; j < 4; ++j) {
            const int row = bm0 + mi * 16 + r0 + j;
            float* yrow = Y + (size_t)row * (NGRP * DOUT) + g * DOUT + wn;
#pragma unroll
            for (int ni = 0; ni < 4; ++ni)
                yrow[ni * 16 + c] = acc[mi][ni][j] + bias_n[ni];
        }
    }
#undef ISSUE_A
#undef CVT_WRITE_A
#undef DMA_B
#undef COMPUTE
}

extern "C" void kernel_launch(void* const* d_in, const int* in_sizes, int n_in,
                              void* d_out, int out_size, void* d_ws, size_t ws_size,
                              hipStream_t stream) {
    const float* X    = (const float*)d_in[0];
    const float* W    = (const float*)d_in[1];
    const float* Bias = (const float*)d_in[2];
    float* Y          = (float*)d_out;
    __bf16* Wb        = (__bf16*)d_ws;   // 8 MB scratch

    // prepass: 16*512*512 = 4M elems / (256 thr * 8 elems) = 2048 blocks
    wcvt_kernel<<<2048, 256, 0, stream>>>(W, Wb);

    const int grid = NGRP * (BATCH / BM);  // 16*32 = 512
    MultiLinear_48498770706571_kernel<<<grid, 512, 0, stream>>>(X, Wb, Bias, Y);
}

// Round 20
// 74.963 us; speedup vs baseline: 1.1295x; 1.1295x over previous
//
#include <hip/hip_runtime.h>
#include <hip/hip_bf16.h>

// MultiLinear: y[b,g,o] = sum_i x[b,g,i] * W[g,o,i] + bias[g,o]
// B=4096, G=16, DIN=512, DOUT=512, fp32 in/out.
// FINAL = R15 (best of 19 rounds, 72.6us, 473 TF):
//  - X READ ONCE: BN=512 (full DOUT) -> fp32 X (the dominant traffic term;
//    dur tracked X-read volume across all rounds) read exactly once.
//  - W->bf16 prepass (8 MB d_ws); B staged via global_load_lds DMA
//    (zero VALU/regs/ds_writes on the B path), W L2-resident per XCD.
//  - A reg-staged fp32->bf16 distance-1 (32 regs), cvt at produce time.
//  - chunk-XOR LDS swizzle both sides (verified 0 bank conflicts, R13).
//  - counted vmcnt: per-tile wait drains only the B-DMA, never the A
//    prefetch; one raw lgkm-only s_barrier per K-tile.
//  - XCD-chunked blockIdx swizzle (FETCH 309->71 MB over the session).
// Falsified alternatives (each regressed): occupancy-first (R7/R10/R16/R17),
// phase-split T3/T4/T5 (R5/R14/R18), all-DMA (R11/R12), BK=128 (R19).

#define BATCH 4096
#define NGRP  16
#define DIN   512
#define DOUT  512

#define BM 128
#define BN 512
#define BK 64
#define NT (DIN / BK)   // 8 K-tiles

typedef __bf16 bf16x8 __attribute__((ext_vector_type(8)));
typedef float  f32x4  __attribute__((ext_vector_type(4)));
typedef const __attribute__((address_space(1))) void gas_void;
typedef __attribute__((address_space(3))) void las_void;

// ---------- prepass: W fp32 -> bf16 into d_ws ----------
__global__ __launch_bounds__(256)
void wcvt_kernel(const float* __restrict__ W, __bf16* __restrict__ Wb) {
    const int i = (blockIdx.x * 256 + threadIdx.x) * 8;
    f32x4 a = *(const f32x4*)(W + i);
    f32x4 b = *(const f32x4*)(W + i + 4);
    bf16x8 v;
#pragma unroll
    for (int j = 0; j < 4; ++j) { v[j] = (__bf16)a[j]; v[j + 4] = (__bf16)b[j]; }
    *(bf16x8*)(Wb + i) = v;
}

// ---------- main GEMM ----------
__global__ __launch_bounds__(512, 2)
void MultiLinear_48498770706571_kernel(const float* __restrict__ X,
                                       const __bf16* __restrict__ Wb,
                                       const float* __restrict__ Bias,
                                       float* __restrict__ Y) {
    // 512 blocks / 8 XCDs = 64 consecutive tiles (2 full groups) per XCD.
    const int bid = (blockIdx.x & 7) * 64 + (blockIdx.x >> 3);
    const int g   = bid >> 5;          // 32 m-tiles per group, 1 n-tile
    const int mt  = bid & 31;
    const int bm0 = mt * BM;

    __shared__ __bf16 As[2][BM * BK];    // 32 KB: linear 128B rows, chunk-swz
    __shared__ __bf16 BsF[2][BN * BK];   // 128 KB: linear, DMA, chunk-swz

    const int tid  = threadIdx.x;
    const int lane = tid & 63;
    const int w    = tid >> 6;        // 0..7
    const int wn   = w * 64;          // wave n-offset (wm = 0 for all)
    const int l15  = lane & 15;
    const int q    = lane >> 4;       // 0..3

    // A staging: 4 thr/row, 16 floats each; 128 rows by 512 threads.
    const int srow = tid >> 2;        // 0..127
    const int sc2  = (tid & 3) * 2;   // first 16B-chunk (of 8) this thr writes
    const float* pA = X + (size_t)(bm0 + srow) * (NGRP * DIN) + g * DIN + (tid & 3) * 16;

    // B DMA geometry: per wave 64 rows; 8 issues of 1 KB (8 rows x 128 B).
    const int drow_l = lane >> 3;     // 0..7 row within instr
    const int dch    = lane & 7;      // 16B chunk within row
    const __bf16* wbase = Wb + (size_t)g * (DOUT * DIN);

    f32x4 ra[4];   // 16 VGPRs in flight (A only; B is DMA)

#define ISSUE_A(k0)                                                        \
    do {                                                                   \
        const f32x4* qa = (const f32x4*)(pA + (k0));                       \
        ra[0] = qa[0]; ra[1] = qa[1]; ra[2] = qa[2]; ra[3] = qa[3];        \
    } while (0)

    // A write: row srow, logical chunks sc2, sc2+1 -> physical chunk ^ (srow&7)
#define CVT_WRITE_A(buf)                                                   \
    do {                                                                   \
        bf16x8 v0, v1;                                                     \
        _Pragma("unroll")                                                  \
        for (int j = 0; j < 4; ++j) {                                      \
            v0[j] = (__bf16)ra[0][j]; v0[j + 4] = (__bf16)ra[1][j];        \
            v1[j] = (__bf16)ra[2][j]; v1[j + 4] = (__bf16)ra[3][j];        \
        }                                                                  \
        const int s = srow & 7;                                            \
        __bf16* base = &As[buf][srow * BK];                                \
        *(bf16x8*)&base[((sc2 ^ s) << 3)]       = v0;                      \
        *(bf16x8*)&base[(((sc2 + 1) ^ s) << 3)] = v1;                      \
    } while (0)

    // B: LDS linear dest; global source pre-swizzled; reads swizzle back.
#define DMA_B(kt, buf)                                                     \
    do {                                                                   \
        const size_t k0 = (size_t)(kt) * BK;                               \
        _Pragma("unroll")                                                  \
        for (int qq = 0; qq < 8; ++qq) {                                   \
            const int row = (w << 6) + (qq << 3) + drow_l;                 \
            const __bf16* gp = wbase + (size_t)row * DIN + k0              \
                               + ((dch ^ (row & 7)) << 3);                 \
            __builtin_amdgcn_global_load_lds(                              \
                (gas_void*)gp,                                             \
                (las_void*)&BsF[buf][(w << 12) + (qq << 9)], 16, 0, 0);    \
        }                                                                  \
    } while (0)

#define COMPUTE(buf)                                                       \
    do {                                                                   \
        _Pragma("unroll")                                                  \
        for (int kk = 0; kk < 2; ++kk) {                                   \
            bf16x8 af[8], bfr[4];                                          \
            _Pragma("unroll")                                              \
            for (int mi = 0; mi < 8; ++mi) {                               \
                const int row = mi * 16 + l15;                             \
                const int ch  = ((kk << 2) + q) ^ (row & 7);               \
                af[mi] = *(const bf16x8*)&As[buf][row * BK + (ch << 3)];   \
            }                                                              \
            _Pragma("unroll")                                              \
            for (int ni = 0; ni < 4; ++ni) {                               \
                const int brow = wn + ni * 16 + l15;                       \
                const int ch = ((kk << 2) + q) ^ (brow & 7);               \
                bfr[ni] = *(const bf16x8*)&BsF[buf][brow * BK + (ch << 3)]; \
            }                                                              \
            _Pragma("unroll")                                              \
            for (int mi = 0; mi < 8; ++mi)                                 \
                _Pragma("unroll")                                          \
                for (int ni = 0; ni < 4; ++ni)                             \
                    acc[mi][ni] = __builtin_amdgcn_mfma_f32_16x16x32_bf16( \
                        af[mi], bfr[ni], acc[mi][ni], 0, 0, 0);            \
        }                                                                  \
    } while (0)

    f32x4 acc[8][4];
#pragma unroll
    for (int mi = 0; mi < 8; ++mi)
#pragma unroll
        for (int ni = 0; ni < 4; ++ni) acc[mi][ni] = f32x4{0.f, 0.f, 0.f, 0.f};

    // prologue: A(0) regs + DMA B(0) into buf0; write A(0); prefetch A(1).
    ISSUE_A(0);
    DMA_B(0, 0);
    CVT_WRITE_A(0);      // compiler waits ra(0) (vmcnt 8): DMA(0) in flight
    ISSUE_A(BK);         // outstanding: DMA(0)[8] + A(1)[4]

    for (int kt = 0; kt < NT; ++kt) {
        const int cur = kt & 1;
        // Drain DMA(kt): outstanding = DMA(kt)[8 oldest] + ra(kt+1)[4 newer].
        if (kt + 1 < NT)
            asm volatile("s_waitcnt vmcnt(4)" ::: "memory");
        else
            asm volatile("s_waitcnt vmcnt(0)" ::: "memory");  // tail: DMA only
        asm volatile("s_waitcnt lgkmcnt(0)" ::: "memory");
        __builtin_amdgcn_s_barrier();

        // after barrier: all waves done reading buf cur^1 -> WAR-safe refill.
        if (kt + 1 < NT) DMA_B(kt + 1, cur ^ 1);

        COMPUTE(cur);

        if (kt + 1 < NT) {
            CVT_WRITE_A(cur ^ 1);          // drains ra(kt+1), DMA stays in flight
            if (kt + 2 < NT) ISSUE_A((kt + 2) * BK);
        }
    }

    // epilogue: C/D layout col = lane&15, row = (lane>>4)*4 + j (verified R1)
    const int r0 = (lane >> 4) * 4;
    const int c  = lane & 15;
    float bias_n[4];
#pragma unroll
    for (int ni = 0; ni < 4; ++ni)
        bias_n[ni] = Bias[g * DOUT + wn + ni * 16 + c];
#pragma unroll
    for (int mi = 0; mi < 8; ++mi) {
#pragma unroll
        for (int j = 0; j < 4; ++j) {
            const int row = bm0 + mi * 16 + r0 + j;
            float* yrow = Y + (size_t)row * (NGRP * DOUT) + g * DOUT + wn;
#pragma unroll
            for (int ni = 0; ni < 4; ++ni)
                yrow[ni * 16 + c] = acc[mi][ni][j] + bias_n[ni];
        }
    }
#undef ISSUE_A
#undef CVT_WRITE_A
#undef DMA_B
#undef COMPUTE
}

extern "C" void kernel_launch(void* const* d_in, const int* in_sizes, int n_in,
                              void* d_out, int out_size, void* d_ws, size_t ws_size,
                              hipStream_t stream) {
    const float* X    = (const float*)d_in[0];
    const float* W    = (const float*)d_in[1];
    const float* Bias = (const float*)d_in[2];
    float* Y          = (float*)d_out;
    __bf16* Wb        = (__bf16*)d_ws;   // 8 MB scratch

    // prepass: 16*512*512 = 4M elems / (256 thr * 8 elems) = 2048 blocks
    wcvt_kernel<<<2048, 256, 0, stream>>>(W, Wb);

    const int grid = NGRP * (BATCH / BM);  // 16*32 = 512
    MultiLinear_48498770706571_kernel<<<grid, 512, 0, stream>>>(X, Wb, Bias, Y);
}